// Round 10
// baseline (107.280 us; speedup 1.0000x reference)
//
#include <hip/hip_runtime.h>
#include <math.h>

// SpectralConvND: rfft2 -> 32x32 mode mixing -> irfft2 as truncated DFT matmuls.
// Round 10: kA = software-pipelined staged version. x quarters (128 rows x 64 w)
// are staged fp32->bf16 into a double-buffered LDS tile with perfectly
// coalesced loads; loads run 2 quarters ahead of compute (static reg rotation).
// D-table A-fragments come from global (L2-hot 32KB). One barrier per quarter.
// kB/k3/kSetup verbatim R9.
//
// x(16,32,256,256) f32; coeff(32r,32c,32i,32j) x2; proj(32o,32r); out(16,32,256,256) f32

#define THETA (6.283185307179586f / 256.0f)

typedef float f32x4 __attribute__((ext_vector_type(4)));
typedef __bf16 bf16x8 __attribute__((ext_vector_type(8)));

__device__ __forceinline__ ushort f2bf(float f) {  // manual RNE (cold paths)
    uint b = __float_as_uint(f);
    b += 0x7FFF + ((b >> 16) & 1);
    return (ushort)(b >> 16);
}
__device__ __forceinline__ ushort bfc(float f) {   // native cast
    __bf16 h = (__bf16)f;
    return __builtin_bit_cast(ushort, h);
}

// ---- kSetup: twiddle tables (blocks 0..127) + Wt projection (blocks 128..1151)
// Dbf[jr][w]  (64x256): jr=2j -> cos(2pi jw/256), jr=2j+1 -> -sin   (fwd DFT rows)
// Gbf[w][kc]  (256x64): kc=2j -> cos, kc=2j+1 -> +sin                (inv-W, B side)
// Ebf[h][ir]  (256x64): ir=2i -> cos, ir=2i+1 -> -sin                (inv-H rows)
// Wt[o,c,i,j] = sum_r proj[o,r] * (cr + i*ci)[r,c,i,j]
__global__ void kSetup(const float* __restrict__ proj, const float* __restrict__ cr,
                       const float* __restrict__ ci, ushort* __restrict__ Dbf,
                       ushort* __restrict__ Gbf, ushort* __restrict__ Ebf,
                       float2* __restrict__ Wt) {
    int blk = blockIdx.x, tid = threadIdx.x;
    if (blk < 64) {
        float s, c;
        int jr = blk, w = tid;
        __sincosf((((jr >> 1) * w) & 255) * THETA, &s, &c);
        Dbf[jr * 256 + w] = (jr & 1) ? f2bf(-s) : f2bf(c);
        Gbf[w * 64 + jr]  = (jr & 1) ? f2bf(s)  : f2bf(c);
        return;
    }
    if (blk < 128) {
        float s, c;
        int e = (blk - 64) * 256 + tid;
        int h = e >> 6, ir = e & 63;
        __sincosf((((ir >> 1) * h) & 255) * THETA, &s, &c);
        Ebf[h * 64 + ir] = (ir & 1) ? f2bf(-s) : f2bf(c);
        return;
    }
    __shared__ float2 co[32][33];
    __shared__ float pr[32 * 32];
    int bb = blk - 128;
    int c = bb >> 5;
    int i = bb & 31;
    for (int idx = tid; idx < 1024; idx += 256) pr[idx] = proj[idx];
    for (int idx = tid; idx < 1024; idx += 256) {
        int r = idx >> 5, j = idx & 31;
        int g = ((r * 32 + c) * 32 + i) * 32 + j;
        co[r][j] = make_float2(cr[g], ci[g]);
    }
    __syncthreads();
    int j = tid & 31, og = tid >> 5;
    for (int oo = 0; oo < 4; ++oo) {
        int o = og * 4 + oo;
        float wr = 0.f, wi = 0.f;
        #pragma unroll
        for (int r = 0; r < 32; ++r) {
            float p = pr[o * 32 + r];
            float2 v = co[r][j];
            wr += p * v.x;
            wi += p * v.y;
        }
        Wt[((o * 32 + c) * 32 + i) * 32 + j] = make_float2(wr, wi);
    }
}

// staging helpers for kA (static after inline + outer unroll)
__device__ __forceinline__ void loadQ(const float4* __restrict__ xp4, int tid,
                                      int qq, float4 xv[4]) {
    #pragma unroll
    for (int k = 0; k < 4; ++k) {
        int idx = tid + 512 * k;                 // row = idx>>4 (0..127), f4 = idx&15
        xv[k] = xp4[((qq >> 2) * 128 + (idx >> 4)) * 64 + (qq & 3) * 16 + (idx & 15)];
    }
}
__device__ __forceinline__ void writeQ(ushort* __restrict__ buf, int tid,
                                       const float4 xv[4]) {
    #pragma unroll
    for (int k = 0; k < 4; ++k) {
        int idx = tid + 512 * k;
        ushort4 u = make_ushort4(bfc(xv[k].x), bfc(xv[k].y), bfc(xv[k].z), bfc(xv[k].w));
        *(ushort4*)&buf[(idx >> 4) * 72 + (idx & 15) * 4] = u;
    }
}

// ---- kA (fused k1+k2, 8 waves, pipelined staging): per (b,c):
//      x -> [W-DFT MFMA] -> Y1(LDS) -> [H-DFT MFMA] -> combine -> Xf[b,c,i,j]
__global__ void __launch_bounds__(512) kA(const float* __restrict__ x,
                                          const ushort* __restrict__ Dbf,
                                          float2* __restrict__ Xf) {
    __shared__ __align__(16) ushort Buf[2][128 * 72];  // 36.9 KB x-quarter dbuf
    __shared__ __align__(16) ushort Yl[64 * 264];      // 33.8 KB
    int bc = blockIdx.x;
    int tid = threadIdx.x;
    int l = tid & 63, wv = tid >> 6;   // wv 0..7
    int lr = l & 15, kg = l >> 4;

    const float4* xp4 = (const float4*)(x + (size_t)bc * 65536);

    float4 xA[4], xB[4];
    loadQ(xp4, tid, 0, xA);
    loadQ(xp4, tid, 1, xB);
    writeQ(Buf[0], tid, xA);
    __syncthreads();

    f32x4 acc1[4];
    #pragma unroll
    for (int qq = 0; qq < 8; ++qq) {   // qq = hh*4 + w-quarter; compile-time
        if ((qq & 3) == 0) {
            #pragma unroll
            for (int mt = 0; mt < 4; ++mt) acc1[mt] = (f32x4){0.f, 0.f, 0.f, 0.f};
        }
        // issue loads 2 quarters ahead (into the parity buffer just freed)
        if (qq < 6) {
            if ((qq & 1) == 0) loadQ(xp4, tid, qq + 2, xA);
            else               loadQ(xp4, tid, qq + 2, xB);
        }
        // MFMA on Buf[qq&1]; A-fragments from global D-table (L2-hot)
        #pragma unroll
        for (int ks = 0; ks < 2; ++ks) {
            bf16x8 a[4], b;
            b = *(const bf16x8*)&Buf[qq & 1][(wv * 16 + lr) * 72 + ks * 32 + kg * 8];
            #pragma unroll
            for (int mt = 0; mt < 4; ++mt)
                a[mt] = *(const bf16x8*)&Dbf[(mt * 16 + lr) * 256 + (qq & 3) * 64 + ks * 32 + kg * 8];
            #pragma unroll
            for (int mt = 0; mt < 4; ++mt)
                acc1[mt] = __builtin_amdgcn_mfma_f32_16x16x32_bf16(a[mt], b, acc1[mt], 0, 0, 0);
        }
        // convert + LDS-write next quarter into the buffer read last quarter
        if (qq < 7) {
            if ((qq & 1) == 0) writeQ(Buf[1], tid, xB);
            else               writeQ(Buf[0], tid, xA);
        }
        // end of hh: flush Y1 rows (row-permuted for MFMA2's B operand)
        if ((qq & 3) == 3) {
            #pragma unroll
            for (int mt = 0; mt < 4; ++mt)
                #pragma unroll
                for (int r = 0; r < 4; ++r) {
                    int jr = mt * 16 + kg * 4 + r;
                    int row = ((jr & 1) << 5) | (jr >> 1);
                    int h = (qq >> 2) * 128 + wv * 16 + lr;
                    Yl[row * 264 + h] = bfc(acc1[mt][r]);
                }
        }
        __syncthreads();
    }
    // MFMA2: P = D(64 ir x 256 h) x Yl(64 rows x 256 h); A from global Dbf
    // waves 0-3: ir-tiles {0,1}, n-cols (wv&3)*16; waves 4-7: ir-tiles {2,3}
    int mh = (wv >> 2) * 2;
    int nc4 = (wv & 3) * 16;
    f32x4 acc2[2];
    #pragma unroll
    for (int m2 = 0; m2 < 2; ++m2) acc2[m2] = (f32x4){0.f, 0.f, 0.f, 0.f};
    #pragma unroll
    for (int ks = 0; ks < 8; ++ks) {
        bf16x8 a[2], b;
        #pragma unroll
        for (int m2 = 0; m2 < 2; ++m2)
            a[m2] = *(const bf16x8*)&Dbf[((mh + m2) * 16 + lr) * 256 + ks * 32 + kg * 8];
        b = *(const bf16x8*)&Yl[(nc4 + lr) * 264 + ks * 32 + kg * 8];
        #pragma unroll
        for (int m2 = 0; m2 < 2; ++m2)
            acc2[m2] = __builtin_amdgcn_mfma_f32_16x16x32_bf16(a[m2], b, acc2[m2], 0, 0, 0);
    }
    // combine via Ol (aliases Buf; all Buf reads finished before final loop barrier)
    float* Ol = (float*)Buf;           // [64 m][68 stride] = 17.4 KB
    #pragma unroll
    for (int m2 = 0; m2 < 2; ++m2)
        #pragma unroll
        for (int r = 0; r < 4; ++r)
            Ol[((mh + m2) * 16 + kg * 4 + r) * 68 + nc4 + lr] = acc2[m2][r];
    __syncthreads();
    // Xr = P[2i][j] - P[2i+1][32+j]; Xi = P[2i][32+j] + P[2i+1][j]
    #pragma unroll
    for (int q = 0; q < 2; ++q) {
        int idx = tid + 512 * q;
        int i = idx >> 5, j = idx & 31;
        float Xr = Ol[(2 * i) * 68 + j] - Ol[(2 * i + 1) * 68 + 32 + j];
        float Xi = Ol[(2 * i) * 68 + 32 + j] + Ol[(2 * i + 1) * 68 + j];
        Xf[(size_t)bc * 1024 + i * 32 + j] = make_float2(Xr, Xi);
    }
}

// ---- K3: Of[b,o,i,j] = sum_c Xf[b,c,i,j] * Wt[o,c,i,j] ----------------------
__global__ void k3(const float2* __restrict__ Xf, const float2* __restrict__ Wt,
                   float2* __restrict__ Of) {
    __shared__ float2 xs[32][33];  // [c][j]
    int bid = blockIdx.x;          // b*32 + i
    int i = bid & 31, b = bid >> 5;
    int tid = threadIdx.x;
    for (int idx = tid; idx < 1024; idx += 256) {
        int c = idx >> 5, j = idx & 31;
        xs[c][j] = Xf[((b * 32 + c) * 32 + i) * 32 + j];
    }
    __syncthreads();
    int j = tid & 31, og = tid >> 5;
    for (int oo = 0; oo < 4; ++oo) {
        int o = og * 4 + oo;
        float orr = 0.f, oi = 0.f;
        for (int c = 0; c < 32; ++c) {
            float2 xv = xs[c][j];
            float2 wv = Wt[((o * 32 + c) * 32 + i) * 32 + j];
            orr += xv.x * wv.x - xv.y * wv.y;
            oi  += xv.x * wv.y + xv.y * wv.x;
        }
        Of[((b * 32 + o) * 32 + i) * 32 + j] = make_float2(orr, oi);
    }
}

// ---- kB (fused k4+k5, 8 waves): per (b,o): Of -> [inv-W MFMA] -> T2(LDS) ->
//      [inv-H MFMA, swapped] -> out[b,o,:,:]
__global__ void __launch_bounds__(512) kB(const float2* __restrict__ Of,
                                          const ushort* __restrict__ Gbf,
                                          const ushort* __restrict__ Ebf,
                                          float* __restrict__ out) {
    __shared__ __align__(16) ushort Al[64 * 72];    // 9.2 KB
    __shared__ __align__(16) ushort Tl[256 * 72];   // 36.9 KB, [w][kr]
    int bo = blockIdx.x;
    int tid = threadIdx.x;
    int l = tid & 63, wv = tid >> 6;   // wv 0..7
    int lr = l & 15, kg = l >> 4;
    // A = interleaved [cj*Or, -cj*Oi; cj*Oi, cj*Or] / 65536
    #pragma unroll
    for (int q = 0; q < 2; ++q) {
        int idx = tid + 512 * q;
        int i = idx >> 5, j = idx & 31;
        float2 v = Of[(size_t)bo * 1024 + idx];
        float sc = (j ? 2.0f : 1.0f) * (1.0f / 65536.0f);
        Al[(2 * i) * 72 + 2 * j]         = bfc(sc * v.x);
        Al[(2 * i) * 72 + 2 * j + 1]     = bfc(-sc * v.y);
        Al[(2 * i + 1) * 72 + 2 * j]     = bfc(sc * v.y);
        Al[(2 * i + 1) * 72 + 2 * j + 1] = bfc(sc * v.x);
    }
    __syncthreads();
    {   // MFMA1: T2[kr 64][w 256] = Al x Gbf; each wave covers 32 w (2 nt)
        f32x4 acc[4][2];
        #pragma unroll
        for (int mt = 0; mt < 4; ++mt)
            #pragma unroll
            for (int nt = 0; nt < 2; ++nt)
                acc[mt][nt] = (f32x4){0.f, 0.f, 0.f, 0.f};
        #pragma unroll
        for (int ks = 0; ks < 2; ++ks) {
            bf16x8 a[4], b[2];
            #pragma unroll
            for (int mt = 0; mt < 4; ++mt)
                a[mt] = *(const bf16x8*)&Al[(mt * 16 + lr) * 72 + ks * 32 + kg * 8];
            #pragma unroll
            for (int nt = 0; nt < 2; ++nt)
                b[nt] = *(const bf16x8*)&Gbf[(wv * 32 + nt * 16 + lr) * 64 + ks * 32 + kg * 8];
            #pragma unroll
            for (int mt = 0; mt < 4; ++mt)
                #pragma unroll
                for (int nt = 0; nt < 2; ++nt)
                    acc[mt][nt] = __builtin_amdgcn_mfma_f32_16x16x32_bf16(
                        a[mt], b[nt], acc[mt][nt], 0, 0, 0);
        }
        // write T2 to LDS transposed: Tl[w][kr], 8B per (mt,nt)
        #pragma unroll
        for (int mt = 0; mt < 4; ++mt) {
            int kr0 = mt * 16 + kg * 4;
            #pragma unroll
            for (int nt = 0; nt < 2; ++nt) {
                int w = wv * 32 + nt * 16 + lr;
                ushort4 u = make_ushort4(bfc(acc[mt][nt][0]), bfc(acc[mt][nt][1]),
                                         bfc(acc[mt][nt][2]), bfc(acc[mt][nt][3]));
                *(ushort4*)&Tl[w * 72 + kr0] = u;
            }
        }
    }
    __syncthreads();
    // MFMA2 (swapped): A=Tl (w rows), B=Ebf (h rows); wave covers 32 h (2 ht);
    // regs hold 4 consecutive w at fixed h -> float4 stores.
    float* op = out + (size_t)bo * 65536;
    for (int nc = 0; nc < 4; ++nc) {
        f32x4 acc[4][2];               // [wt][ht]
        #pragma unroll
        for (int wt = 0; wt < 4; ++wt)
            #pragma unroll
            for (int ht = 0; ht < 2; ++ht)
                acc[wt][ht] = (f32x4){0.f, 0.f, 0.f, 0.f};
        #pragma unroll
        for (int ks = 0; ks < 2; ++ks) {
            bf16x8 aw[4], bh[2];
            #pragma unroll
            for (int wt = 0; wt < 4; ++wt)
                aw[wt] = *(const bf16x8*)&Tl[(nc * 64 + wt * 16 + lr) * 72 + ks * 32 + kg * 8];
            #pragma unroll
            for (int ht = 0; ht < 2; ++ht)
                bh[ht] = *(const bf16x8*)&Ebf[((wv * 2 + ht) * 16 + lr) * 64 + ks * 32 + kg * 8];
            #pragma unroll
            for (int wt = 0; wt < 4; ++wt)
                #pragma unroll
                for (int ht = 0; ht < 2; ++ht)
                    acc[wt][ht] = __builtin_amdgcn_mfma_f32_16x16x32_bf16(
                        aw[wt], bh[ht], acc[wt][ht], 0, 0, 0);
        }
        #pragma unroll
        for (int wt = 0; wt < 4; ++wt)
            #pragma unroll
            for (int ht = 0; ht < 2; ++ht) {
                int h = (wv * 2 + ht) * 16 + lr;
                int w0 = nc * 64 + wt * 16 + kg * 4;
                *(f32x4*)&op[h * 256 + w0] = acc[wt][ht];
            }
    }
}

extern "C" void kernel_launch(void* const* d_in, const int* in_sizes, int n_in,
                              void* d_out, int out_size, void* d_ws, size_t ws_size,
                              hipStream_t stream) {
    const float* x    = (const float*)d_in[0];
    const float* cr   = (const float*)d_in[1];
    const float* ci   = (const float*)d_in[2];
    const float* proj = (const float*)d_in[3];
    float* out = (float*)d_out;
    char* ws = (char*)d_ws;

    // ws layout (16,875,520 B used):
    //   Xf  @ 0         4,194,304  (float2)
    //   Wt  @ 4MiB      8,388,608  (float2)
    //   Of  @ 12MiB     4,194,304  (float2)
    //   Dbf @ 16MiB        32,768  (bf16 64x256)
    //   Gbf @ +32KB        32,768  (bf16 256x64)
    //   Ebf @ +64KB        32,768  (bf16 256x64)
    float2* Xf  = (float2*)ws;
    float2* Wt  = (float2*)(ws + 4194304);
    float2* Of  = (float2*)(ws + 12582912);
    ushort* Dbf = (ushort*)(ws + 16777216);
    ushort* Gbf = (ushort*)(ws + 16777216 + 32768);
    ushort* Ebf = (ushort*)(ws + 16777216 + 65536);

    kSetup<<<1152, 256, 0, stream>>>(proj, cr, ci, Dbf, Gbf, Ebf, Wt);
    kA<<<512, 512, 0, stream>>>(x, Dbf, Xf);
    k3<<<512, 256, 0, stream>>>(Xf, Wt, Of);
    kB<<<512, 512, 0, stream>>>(Of, Gbf, Ebf, out);
}

// Round 11
// 83.848 us; speedup vs baseline: 1.2794x; 1.2794x over previous
//
#include <hip/hip_runtime.h>
#include <math.h>

// SpectralConvND: rfft2 -> 32x32 mode mixing -> irfft2 as truncated DFT matmuls.
// Round 11: kA reverted to the proven R9 reg-fragment version (R10's
// barrier-per-quarter pipeline regressed). One change: k3 fused into kB's
// staging phase (Of computed in-register from L2-resident Xf/Wt), killing the
// k3 launch + Of round-trip. 3 kernels total.
//
// x(16,32,256,256) f32; coeff(32r,32c,32i,32j) x2; proj(32o,32r); out(16,32,256,256) f32

#define THETA (6.283185307179586f / 256.0f)

typedef float f32x4 __attribute__((ext_vector_type(4)));
typedef __bf16 bf16x8 __attribute__((ext_vector_type(8)));

__device__ __forceinline__ ushort f2bf(float f) {  // manual RNE (cold paths)
    uint b = __float_as_uint(f);
    b += 0x7FFF + ((b >> 16) & 1);
    return (ushort)(b >> 16);
}
__device__ __forceinline__ ushort bfc(float f) {   // native cast
    __bf16 h = (__bf16)f;
    return __builtin_bit_cast(ushort, h);
}

// ---- kSetup: twiddle tables (blocks 0..127) + Wt projection (blocks 128..1151)
// Dbf[jr][w]  (64x256): jr=2j -> cos(2pi jw/256), jr=2j+1 -> -sin   (fwd DFT rows)
// Gbf[w][kc]  (256x64): kc=2j -> cos, kc=2j+1 -> +sin                (inv-W, B side)
// Ebf[h][ir]  (256x64): ir=2i -> cos, ir=2i+1 -> -sin                (inv-H rows)
// Wt[o,c,i,j] = sum_r proj[o,r] * (cr + i*ci)[r,c,i,j]
__global__ void kSetup(const float* __restrict__ proj, const float* __restrict__ cr,
                       const float* __restrict__ ci, ushort* __restrict__ Dbf,
                       ushort* __restrict__ Gbf, ushort* __restrict__ Ebf,
                       float2* __restrict__ Wt) {
    int blk = blockIdx.x, tid = threadIdx.x;
    if (blk < 64) {
        float s, c;
        int jr = blk, w = tid;
        __sincosf((((jr >> 1) * w) & 255) * THETA, &s, &c);
        Dbf[jr * 256 + w] = (jr & 1) ? f2bf(-s) : f2bf(c);
        Gbf[w * 64 + jr]  = (jr & 1) ? f2bf(s)  : f2bf(c);
        return;
    }
    if (blk < 128) {
        float s, c;
        int e = (blk - 64) * 256 + tid;
        int h = e >> 6, ir = e & 63;
        __sincosf((((ir >> 1) * h) & 255) * THETA, &s, &c);
        Ebf[h * 64 + ir] = (ir & 1) ? f2bf(-s) : f2bf(c);
        return;
    }
    __shared__ float2 co[32][33];
    __shared__ float pr[32 * 32];
    int bb = blk - 128;
    int c = bb >> 5;
    int i = bb & 31;
    for (int idx = tid; idx < 1024; idx += 256) pr[idx] = proj[idx];
    for (int idx = tid; idx < 1024; idx += 256) {
        int r = idx >> 5, j = idx & 31;
        int g = ((r * 32 + c) * 32 + i) * 32 + j;
        co[r][j] = make_float2(cr[g], ci[g]);
    }
    __syncthreads();
    int j = tid & 31, og = tid >> 5;
    for (int oo = 0; oo < 4; ++oo) {
        int o = og * 4 + oo;
        float wr = 0.f, wi = 0.f;
        #pragma unroll
        for (int r = 0; r < 32; ++r) {
            float p = pr[o * 32 + r];
            float2 v = co[r][j];
            wr += p * v.x;
            wi += p * v.y;
        }
        Wt[((o * 32 + c) * 32 + i) * 32 + j] = make_float2(wr, wi);
    }
}

// ---- kA (fused k1+k2, 8 waves, reg-fragment x) — R9-proven version ----------
__global__ void __launch_bounds__(512) kA(const float* __restrict__ x,
                                          const ushort* __restrict__ Dbf,
                                          float2* __restrict__ Xf) {
    __shared__ __align__(16) ushort Dl[64 * 264];   // 33.8 KB; aliased Ol f32 later
    __shared__ __align__(16) ushort Yl[64 * 264];   // 33.8 KB
    int bc = blockIdx.x;
    int tid = threadIdx.x;
    int l = tid & 63, wv = tid >> 6;   // wv 0..7
    int lr = l & 15, kg = l >> 4;

    // stage D table (64x256 bf16) once, stride 264
    {
        const uint4* ds = (const uint4*)Dbf;
        #pragma unroll
        for (int q = 0; q < 4; ++q) {
            int idx = tid + 512 * q;       // 2048 x 16B
            int row = idx >> 5, c8 = idx & 31;
            *(uint4*)&Dl[row * 264 + c8 * 8] = ds[idx];
        }
    }
    __syncthreads();

    const float* xp = x + (size_t)bc * 65536;

    #pragma unroll
    for (int hh = 0; hh < 2; ++hh) {
        f32x4 acc1[4];                 // [mt: jr-tiles]; wave's n-tile = 16 h rows
        #pragma unroll
        for (int mt = 0; mt < 4; ++mt) acc1[mt] = (f32x4){0.f, 0.f, 0.f, 0.f};
        const f32x4* rp = (const f32x4*)(xp + (size_t)(hh * 128 + wv * 16 + lr) * 256)
                          + kg * 2;
        #pragma unroll
        for (int wh = 0; wh < 2; ++wh) {
            // issue all 8 independent loads first (static reg array)
            f32x4 xv[8];
            #pragma unroll
            for (int ks = 0; ks < 4; ++ks) {
                xv[2 * ks]     = rp[wh * 32 + ks * 8];
                xv[2 * ks + 1] = rp[wh * 32 + ks * 8 + 1];
            }
            // convert + MFMA (A from LDS D-table)
            #pragma unroll
            for (int ks = 0; ks < 4; ++ks) {
                bf16x8 b;
                #pragma unroll
                for (int e = 0; e < 4; ++e) {
                    b[e]     = (__bf16)xv[2 * ks][e];
                    b[4 + e] = (__bf16)xv[2 * ks + 1][e];
                }
                bf16x8 a[4];
                #pragma unroll
                for (int mt = 0; mt < 4; ++mt)
                    a[mt] = *(const bf16x8*)&Dl[(mt * 16 + lr) * 264 + wh * 128 + ks * 32 + kg * 8];
                #pragma unroll
                for (int mt = 0; mt < 4; ++mt)
                    acc1[mt] = __builtin_amdgcn_mfma_f32_16x16x32_bf16(
                        a[mt], b, acc1[mt], 0, 0, 0);
            }
        }
        // Y1 -> LDS, row-permuted for MFMA2's B operand: row = (im?32:0)+j
        #pragma unroll
        for (int mt = 0; mt < 4; ++mt)
            #pragma unroll
            for (int r = 0; r < 4; ++r) {
                int jr = mt * 16 + kg * 4 + r;
                int row = ((jr & 1) << 5) | (jr >> 1);
                int h = hh * 128 + wv * 16 + lr;
                Yl[row * 264 + h] = bfc(acc1[mt][r]);
            }
    }
    __syncthreads();                  // all Yl written
    // MFMA2: P = D(64 ir x 256 h) x Yl(64 rows x 256 h), A from Dl
    int mh = (wv >> 2) * 2;
    int nc4 = (wv & 3) * 16;
    f32x4 acc2[2];
    #pragma unroll
    for (int m2 = 0; m2 < 2; ++m2) acc2[m2] = (f32x4){0.f, 0.f, 0.f, 0.f};
    #pragma unroll
    for (int ks = 0; ks < 8; ++ks) {
        bf16x8 a[2], b;
        #pragma unroll
        for (int m2 = 0; m2 < 2; ++m2)
            a[m2] = *(const bf16x8*)&Dl[((mh + m2) * 16 + lr) * 264 + ks * 32 + kg * 8];
        b = *(const bf16x8*)&Yl[(nc4 + lr) * 264 + ks * 32 + kg * 8];
        #pragma unroll
        for (int m2 = 0; m2 < 2; ++m2)
            acc2[m2] = __builtin_amdgcn_mfma_f32_16x16x32_bf16(a[m2], b, acc2[m2], 0, 0, 0);
    }
    __syncthreads();                  // all Dl reads done; reuse Dl space as Ol
    float* Ol = (float*)Dl;           // [64 m][68 stride] = 17.4 KB
    #pragma unroll
    for (int m2 = 0; m2 < 2; ++m2)
        #pragma unroll
        for (int r = 0; r < 4; ++r)
            Ol[((mh + m2) * 16 + kg * 4 + r) * 68 + nc4 + lr] = acc2[m2][r];
    __syncthreads();
    // Xr = P[2i][j] - P[2i+1][32+j]; Xi = P[2i][32+j] + P[2i+1][j]
    #pragma unroll
    for (int q = 0; q < 2; ++q) {
        int idx = tid + 512 * q;
        int i = idx >> 5, j = idx & 31;
        float Xr = Ol[(2 * i) * 68 + j] - Ol[(2 * i + 1) * 68 + 32 + j];
        float Xi = Ol[(2 * i) * 68 + 32 + j] + Ol[(2 * i + 1) * 68 + j];
        Xf[(size_t)bc * 1024 + i * 32 + j] = make_float2(Xr, Xi);
    }
}

// ---- kB (fused k3+k4+k5, 8 waves): per (b,o):
//      Of = sum_c Xf[b,c]*Wt[o,c] (in-reg, L2 reads) -> [inv-W MFMA] -> T2(LDS)
//      -> [inv-H MFMA, swapped] -> out[b,o,:,:]
__global__ void __launch_bounds__(512) kB(const float2* __restrict__ Xf,
                                          const float2* __restrict__ Wt,
                                          const ushort* __restrict__ Gbf,
                                          const ushort* __restrict__ Ebf,
                                          float* __restrict__ out) {
    __shared__ __align__(16) ushort Al[64 * 72];    // 9.2 KB
    __shared__ __align__(16) ushort Tl[256 * 72];   // 36.9 KB, [w][kr]
    int bo = blockIdx.x;
    int b = bo >> 5, o = bo & 31;
    int tid = threadIdx.x;
    int l = tid & 63, wv = tid >> 6;   // wv 0..7
    int lr = l & 15, kg = l >> 4;
    // channel mix (old k3) + A build: per thread 2 (i,j) elems
    #pragma unroll
    for (int q = 0; q < 2; ++q) {
        int idx = tid + 512 * q;
        int i = idx >> 5, j = idx & 31;
        const float2* xr = Xf + (size_t)b * 32768 + idx;   // + c*1024
        const float2* wr = Wt + (size_t)o * 32768 + idx;
        float orr = 0.f, oi = 0.f;
        #pragma unroll
        for (int c = 0; c < 32; ++c) {
            float2 xv = xr[c * 1024];
            float2 wv = wr[c * 1024];
            orr += xv.x * wv.x - xv.y * wv.y;
            oi  += xv.x * wv.y + xv.y * wv.x;
        }
        float sc = (j ? 2.0f : 1.0f) * (1.0f / 65536.0f);
        Al[(2 * i) * 72 + 2 * j]         = bfc(sc * orr);
        Al[(2 * i) * 72 + 2 * j + 1]     = bfc(-sc * oi);
        Al[(2 * i + 1) * 72 + 2 * j]     = bfc(sc * oi);
        Al[(2 * i + 1) * 72 + 2 * j + 1] = bfc(sc * orr);
    }
    __syncthreads();
    {   // MFMA1: T2[kr 64][w 256] = Al x Gbf; each wave covers 32 w (2 nt)
        f32x4 acc[4][2];
        #pragma unroll
        for (int mt = 0; mt < 4; ++mt)
            #pragma unroll
            for (int nt = 0; nt < 2; ++nt)
                acc[mt][nt] = (f32x4){0.f, 0.f, 0.f, 0.f};
        #pragma unroll
        for (int ks = 0; ks < 2; ++ks) {
            bf16x8 a[4], b2[2];
            #pragma unroll
            for (int mt = 0; mt < 4; ++mt)
                a[mt] = *(const bf16x8*)&Al[(mt * 16 + lr) * 72 + ks * 32 + kg * 8];
            #pragma unroll
            for (int nt = 0; nt < 2; ++nt)
                b2[nt] = *(const bf16x8*)&Gbf[(wv * 32 + nt * 16 + lr) * 64 + ks * 32 + kg * 8];
            #pragma unroll
            for (int mt = 0; mt < 4; ++mt)
                #pragma unroll
                for (int nt = 0; nt < 2; ++nt)
                    acc[mt][nt] = __builtin_amdgcn_mfma_f32_16x16x32_bf16(
                        a[mt], b2[nt], acc[mt][nt], 0, 0, 0);
        }
        // write T2 to LDS transposed: Tl[w][kr], 8B per (mt,nt)
        #pragma unroll
        for (int mt = 0; mt < 4; ++mt) {
            int kr0 = mt * 16 + kg * 4;
            #pragma unroll
            for (int nt = 0; nt < 2; ++nt) {
                int w = wv * 32 + nt * 16 + lr;
                ushort4 u = make_ushort4(bfc(acc[mt][nt][0]), bfc(acc[mt][nt][1]),
                                         bfc(acc[mt][nt][2]), bfc(acc[mt][nt][3]));
                *(ushort4*)&Tl[w * 72 + kr0] = u;
            }
        }
    }
    __syncthreads();
    // MFMA2 (swapped): A=Tl (w rows), B=Ebf (h rows); wave covers 32 h (2 ht);
    // regs hold 4 consecutive w at fixed h -> float4 stores.
    float* op = out + (size_t)bo * 65536;
    for (int nc = 0; nc < 4; ++nc) {
        f32x4 acc[4][2];               // [wt][ht]
        #pragma unroll
        for (int wt = 0; wt < 4; ++wt)
            #pragma unroll
            for (int ht = 0; ht < 2; ++ht)
                acc[wt][ht] = (f32x4){0.f, 0.f, 0.f, 0.f};
        #pragma unroll
        for (int ks = 0; ks < 2; ++ks) {
            bf16x8 aw[4], bh[2];
            #pragma unroll
            for (int wt = 0; wt < 4; ++wt)
                aw[wt] = *(const bf16x8*)&Tl[(nc * 64 + wt * 16 + lr) * 72 + ks * 32 + kg * 8];
            #pragma unroll
            for (int ht = 0; ht < 2; ++ht)
                bh[ht] = *(const bf16x8*)&Ebf[((wv * 2 + ht) * 16 + lr) * 64 + ks * 32 + kg * 8];
            #pragma unroll
            for (int wt = 0; wt < 4; ++wt)
                #pragma unroll
                for (int ht = 0; ht < 2; ++ht)
                    acc[wt][ht] = __builtin_amdgcn_mfma_f32_16x16x32_bf16(
                        aw[wt], bh[ht], acc[wt][ht], 0, 0, 0);
        }
        #pragma unroll
        for (int wt = 0; wt < 4; ++wt)
            #pragma unroll
            for (int ht = 0; ht < 2; ++ht) {
                int h = (wv * 2 + ht) * 16 + lr;
                int w0 = nc * 64 + wt * 16 + kg * 4;
                *(f32x4*)&op[h * 256 + w0] = acc[wt][ht];
            }
    }
}

extern "C" void kernel_launch(void* const* d_in, const int* in_sizes, int n_in,
                              void* d_out, int out_size, void* d_ws, size_t ws_size,
                              hipStream_t stream) {
    const float* x    = (const float*)d_in[0];
    const float* cr   = (const float*)d_in[1];
    const float* ci   = (const float*)d_in[2];
    const float* proj = (const float*)d_in[3];
    float* out = (float*)d_out;
    char* ws = (char*)d_ws;

    // ws layout (12,681,216 B used):
    //   Xf  @ 0         4,194,304  (float2)
    //   Wt  @ 4MiB      8,388,608  (float2)
    //   Dbf @ 12MiB        32,768  (bf16 64x256)
    //   Gbf @ +32KB        32,768  (bf16 256x64)
    //   Ebf @ +64KB        32,768  (bf16 256x64)
    float2* Xf  = (float2*)ws;
    float2* Wt  = (float2*)(ws + 4194304);
    ushort* Dbf = (ushort*)(ws + 12582912);
    ushort* Gbf = (ushort*)(ws + 12582912 + 32768);
    ushort* Ebf = (ushort*)(ws + 12582912 + 65536);

    kSetup<<<1152, 256, 0, stream>>>(proj, cr, ci, Dbf, Gbf, Ebf, Wt);
    kA<<<512, 512, 0, stream>>>(x, Dbf, Xf);
    kB<<<512, 512, 0, stream>>>(Xf, Wt, Gbf, Ebf, out);
}